// Round 14
// baseline (266.282 us; speedup 1.0000x reference)
//
#include <hip/hip_runtime.h>

typedef __attribute__((ext_vector_type(8))) short short8;   // 8 bf16 in 4 VGPRs
typedef __attribute__((ext_vector_type(4))) float f32x4;    // MFMA accumulator
typedef __attribute__((ext_vector_type(4))) float f4;       // float4 as ext_vector

__device__ inline float dot4(f4 a, f4 b) { return a.x*b.x + a.y*b.y + a.z*b.z + a.w*b.w; }
__device__ inline f4 comb4(f4 s, float al, f4 x, float be, f4 y) { return s + al*x + be*y; }

__device__ inline short bf16rne(float x) {   // f32 -> bf16 bits, round-nearest-even
    unsigned u = __float_as_uint(x);
    u += 0x7FFFu + ((u >> 16) & 1u);
    return (short)(u >> 16);
}
__device__ inline short8 pack_bf16(f4 a, f4 b) {
    short8 r;
    r[0] = bf16rne(a.x); r[1] = bf16rne(a.y); r[2] = bf16rne(a.z); r[3] = bf16rne(a.w);
    r[4] = bf16rne(b.x); r[5] = bf16rne(b.y); r[6] = bf16rne(b.z); r[7] = bf16rne(b.w);
    return r;
}

#define AS1(p) ((const __attribute__((address_space(1))) void*)(p))
#define AS3(p) ((__attribute__((address_space(3))) void*)(p))

// R13 pipeline with the W-gather double-buffer moved from registers to
// wave-private LDS via global_load_lds (per-lane global addr, wave-uniform LDS
// base, lane-linear scatter = identity readback). GW de-registered (L1 re-read
// per iter). Persistent VGPR ~80 -> <=128 tier -> 16 waves/CU; grid 1024 = all
// 4 blocks/CU resident, 8 pipelined iterations/wave. ds_read placed FIRST in
// each phase so conservative vmcnt waits only cover 1-iteration-old loads.
__global__ __launch_bounds__(256, 4)
void encoder_mfma(const int* __restrict__ nodes,
                  const float* __restrict__ W,    // [V,64]
                  const float* __restrict__ L1,   // [B,64]
                  const float* __restrict__ L2,   // [B,64]
                  const float* __restrict__ AW,   // [128]
                  const float* __restrict__ ABv,  // [1]
                  const float* __restrict__ BW,   // [128]
                  const float* __restrict__ BBv,  // [1]
                  const float* __restrict__ GW,   // [64,64] row-major
                  const float* __restrict__ GB,   // [64]
                  float* __restrict__ out,        // [B,64]
                  int nrows)
{
    const int lane = threadIdx.x & 63;
    const int wid  = threadIdx.x >> 6;
    const int m    = lane & 15;   // A row / C col within tile
    const int g    = lane >> 4;   // k-group

    // float4 indices of this lane's k-chunks: k = 8g..8g+7 and 32+8g..32+8g+7
    const int i0 = 2 * g, i1 = 2 * g + 1, i2 = 8 + 2 * g, i3 = 9 + 2 * g;

    // W staging: [wave][buf][j][lane] 16B slots = 32 KB/block, wave-private
    __shared__ f4 ldsW[4][2][4][64];

    const unsigned nGroups = (unsigned)nrows >> 4;           // 32768
    const unsigned stride  = (unsigned)gridDim.x * 4u;       // 4096 waves -> 8 groups each

    const float ab = ABv[0], bb = BBv[0];
    const f4* AWp = reinterpret_cast<const f4*>(AW);
    const f4* BWp = reinterpret_cast<const f4*>(BW);
    float gbvA[4];
#pragma unroll
    for (int t = 0; t < 4; ++t) gbvA[t] = GB[t * 16 + m];

    // issue the 4 gather loads for one group directly into LDS buf (no VGPRs)
    auto issueW = [&](int buf, int nidx) {
        const float* base = W + (unsigned)nidx * 64u;
        f4* d = &ldsW[wid][buf][0][0];
        __builtin_amdgcn_global_load_lds(AS1(base + 4 * i0), AS3(d),       16, 0, 0);
        __builtin_amdgcn_global_load_lds(AS1(base + 4 * i1), AS3(d + 64),  16, 0, 0);
        __builtin_amdgcn_global_load_lds(AS1(base + 4 * i2), AS3(d + 128), 16, 0, 0);
        __builtin_amdgcn_global_load_lds(AS1(base + 4 * i3), AS3(d + 192), 16, 0, 0);
    };

    auto loadStreams = [&](unsigned grpL, f4* x, f4* y) {
        const unsigned row = grpL * 16u + (unsigned)m;
        const f4* L1p = reinterpret_cast<const f4*>(L1 + (size_t)row * 64u);
        const f4* L2p = reinterpret_cast<const f4*>(L2 + (size_t)row * 64u);
        x[0] = __builtin_nontemporal_load(L1p + i0);
        x[1] = __builtin_nontemporal_load(L1p + i1);
        x[2] = __builtin_nontemporal_load(L1p + i2);
        x[3] = __builtin_nontemporal_load(L1p + i3);
        y[0] = __builtin_nontemporal_load(L2p + i0);
        y[1] = __builtin_nontemporal_load(L2p + i1);
        y[2] = __builtin_nontemporal_load(L2p + i2);
        y[3] = __builtin_nontemporal_load(L2p + i3);
    };

    auto computeRest = [&](f4 w0, f4 w1, f4 w2, f4 w3,
                           const f4* x, const f4* y, unsigned grpC) {
        // gates in f32
        float pa = dot4(w0, AWp[i0]) + dot4(w1, AWp[i1])
                 + dot4(w2, AWp[i2]) + dot4(w3, AWp[i3])
                 + dot4(x[0], AWp[16 + i0]) + dot4(x[1], AWp[16 + i1])
                 + dot4(x[2], AWp[16 + i2]) + dot4(x[3], AWp[16 + i3]);
        float pb = dot4(w0, BWp[i0]) + dot4(w1, BWp[i1])
                 + dot4(w2, BWp[i2]) + dot4(w3, BWp[i3])
                 + dot4(y[0], BWp[16 + i0]) + dot4(y[1], BWp[16 + i1])
                 + dot4(y[2], BWp[16 + i2]) + dot4(y[3], BWp[16 + i3]);
        // row m lives on lanes {m, m+16, m+32, m+48}
        pa += __shfl_xor(pa, 16); pa += __shfl_xor(pa, 32);
        pb += __shfl_xor(pb, 16); pb += __shfl_xor(pb, 32);
        const float alpha = pa + ab;
        const float beta  = pb + bb;

        const short8 a0 = pack_bf16(comb4(w0, alpha, x[0], beta, y[0]),
                                    comb4(w1, alpha, x[1], beta, y[1]));
        const short8 a1 = pack_bf16(comb4(w2, alpha, x[2], beta, y[2]),
                                    comb4(w3, alpha, x[3], beta, y[3]));

        const unsigned row0 = grpC * 16u;
        // GW^T B-fragments re-read from L1 (16 KB resident) each iter: frees 32 VGPRs
#pragma unroll
        for (int t = 0; t < 4; ++t) {
            const int n = t * 16 + m;
            const f4* Gp = reinterpret_cast<const f4*>(GW + (unsigned)n * 64u);
            const short8 b0 = pack_bf16(Gp[i0], Gp[i1]);
            const short8 b1 = pack_bf16(Gp[i2], Gp[i3]);
            f32x4 acc;
            acc[0] = gbvA[t]; acc[1] = gbvA[t]; acc[2] = gbvA[t]; acc[3] = gbvA[t];
            acc = __builtin_amdgcn_mfma_f32_16x16x32_bf16(a0, b0, acc, 0, 0, 0);
            acc = __builtin_amdgcn_mfma_f32_16x16x32_bf16(a1, b1, acc, 0, 0, 0);
            // C layout col=lane&15, row=4g+reg (m89-verified)
#pragma unroll
            for (int r = 0; r < 4; ++r) {
                out[(row0 + 4u * (unsigned)g + r) * 64u + (unsigned)n] = acc[r];
            }
        }
    };

    // ---- 2-deep pipeline: nodes 2 ahead, W-in-LDS + streams-in-regs 1 ahead ----
    unsigned grp = (unsigned)blockIdx.x * 4u + (unsigned)wid;
    if (grp >= nGroups) return;

    f4 Ax[4], Ay[4], Bx[4], By[4];
    int nv = nodes[grp * 16u + (unsigned)m];
    issueW(0, nv);
    loadStreams(grp, Ax, Ay);
    unsigned gn = grp + stride;
    int nvN = (gn < nGroups) ? nodes[gn * 16u + (unsigned)m] : 0;

    while (true) {
        // even phase: ds_read buf0 FIRST (all outstanding VMEM is >=1 phase old),
        // then issue next group's loads, then compute/store grp
        f4 w0 = ldsW[wid][0][0][lane];
        f4 w1 = ldsW[wid][0][1][lane];
        f4 w2 = ldsW[wid][0][2][lane];
        f4 w3 = ldsW[wid][0][3][lane];
        const bool hasN = (gn < nGroups);
        if (hasN) {
            issueW(1, nvN);
            loadStreams(gn, Bx, By);
            const unsigned g2 = gn + stride;
            nv = (g2 < nGroups) ? nodes[g2 * 16u + (unsigned)m] : 0;
        }
        computeRest(w0, w1, w2, w3, Ax, Ay, grp);
        if (!hasN) return;
        grp = gn; gn += stride;

        // odd phase: ds_read buf1, issue into buf0, compute/store
        f4 v0 = ldsW[wid][1][0][lane];
        f4 v1 = ldsW[wid][1][1][lane];
        f4 v2 = ldsW[wid][1][2][lane];
        f4 v3 = ldsW[wid][1][3][lane];
        const bool hasN2 = (gn < nGroups);
        if (hasN2) {
            issueW(0, nv);
            loadStreams(gn, Ax, Ay);
            const unsigned g2 = gn + stride;
            nvN = (g2 < nGroups) ? nodes[g2 * 16u + (unsigned)m] : 0;
        }
        computeRest(v0, v1, v2, v3, Bx, By, grp);
        if (!hasN2) return;
        grp = gn; gn += stride;
    }
}

extern "C" void kernel_launch(void* const* d_in, const int* in_sizes, int n_in,
                              void* d_out, int out_size, void* d_ws, size_t ws_size,
                              hipStream_t stream) {
    const int*   nodes = (const int*)  d_in[0];
    const float* W     = (const float*)d_in[1];
    const float* L1    = (const float*)d_in[2];
    const float* L2    = (const float*)d_in[3];
    const float* AW    = (const float*)d_in[4];
    const float* AB    = (const float*)d_in[5];
    const float* BW    = (const float*)d_in[6];
    const float* BB    = (const float*)d_in[7];
    const float* GW    = (const float*)d_in[8];
    const float* GB    = (const float*)d_in[9];
    float* out = (float*)d_out;
    const int nrows = in_sizes[0];  // B = 524288

    // 1024 blocks x 4 waves = 4096 persistent waves, 8 groups each (exact);
    // 4 blocks/CU all-resident at VGPR<=128 + 32KB LDS
    hipLaunchKernelGGL(encoder_mfma, dim3(1024), dim3(256), 0, stream,
                       nodes, W, L1, L2, AW, AB, BW, BB, GW, GB, out, nrows);
}

// Round 15
// 107.680 us; speedup vs baseline: 2.4729x; 2.4729x over previous
//
#include <hip/hip_runtime.h>

typedef __attribute__((ext_vector_type(8))) short short8;   // 8 bf16 in 4 VGPRs
typedef __attribute__((ext_vector_type(4))) float f32x4;    // MFMA accumulator
typedef __attribute__((ext_vector_type(4))) float f4;       // float4 as ext_vector

__device__ inline float dot4(f4 a, f4 b) { return a.x*b.x + a.y*b.y + a.z*b.z + a.w*b.w; }
__device__ inline f4 comb4(f4 s, float al, f4 x, float be, f4 y) { return s + al*x + be*y; }

__device__ inline short bf16rne(float x) {   // f32 -> bf16 bits, round-nearest-even
    unsigned u = __float_as_uint(x);
    u += 0x7FFFu + ((u >> 16) & 1u);
    return (short)(u >> 16);
}
__device__ inline short8 pack_bf16(f4 a, f4 b) {
    short8 r;
    r[0] = bf16rne(a.x); r[1] = bf16rne(a.y); r[2] = bf16rne(a.z); r[3] = bf16rne(a.w);
    r[4] = bf16rne(b.x); r[5] = bf16rne(b.y); r[6] = bf16rne(b.z); r[7] = bf16rne(b.w);
    return r;
}

struct Feats { f4 w[4]; f4 x[4]; f4 y[4]; };   // self / l1 / l2 fragments (48 VGPRs)

// R13 pipeline, restructured so the ENTIRE steady state is ONE basic block:
// exactly 4 groups/wave (32768 groups / 8192 waves), fully unrolled
// load/compute interleave with zero branches. Rationale: every prior round
// wrapped loads in `if(hasN)` + a rotating while-loop; the waitcnt pass is
// conservative across control flow and collapsed the pipeline to vmcnt(0)
// per iteration (measured: ~10-25K cy/iter = serialized chain). Straight-line
// code lets it emit precise vmcnt(12), keeping a full load phase in flight.
// Keeps: (256,1) cap (R13: 144 VGPR no spill), GW frags in regs, nt-loads
// (FETCH 277->204), plain stores (WRITE=131 exact). Zero LDS, zero barriers.
__global__ __launch_bounds__(256, 1)
void encoder_mfma(const int* __restrict__ nodes,
                  const float* __restrict__ W,    // [V,64]
                  const float* __restrict__ L1,   // [B,64]
                  const float* __restrict__ L2,   // [B,64]
                  const float* __restrict__ AW,   // [128]
                  const float* __restrict__ ABv,  // [1]
                  const float* __restrict__ BW,   // [128]
                  const float* __restrict__ BBv,  // [1]
                  const float* __restrict__ GW,   // [64,64] row-major
                  const float* __restrict__ GB,   // [64]
                  float* __restrict__ out,        // [B,64]
                  int nrows)
{
    const int lane = threadIdx.x & 63;
    const int wid  = threadIdx.x >> 6;
    const int m    = lane & 15;   // A row / C col within tile
    const int g    = lane >> 4;   // k-group

    // float4 indices of this lane's k-chunks: k = 8g..8g+7 and 32+8g..32+8g+7
    const int i0 = 2 * g, i1 = 2 * g + 1, i2 = 8 + 2 * g, i3 = 9 + 2 * g;

    const unsigned nGroups = (unsigned)nrows >> 4;           // 32768
    const unsigned stride  = (unsigned)gridDim.x * 4u;       // 8192 waves

    // ---- per-wave invariants: GW^T B-fragments + biases (amortized) ----
    short8 gB0[4], gB1[4];
    float  gbv[4];
#pragma unroll
    for (int t = 0; t < 4; ++t) {
        const int n = t * 16 + m;
        const f4* Gp = reinterpret_cast<const f4*>(GW + (unsigned)n * 64u);
        gB0[t] = pack_bf16(Gp[i0], Gp[i1]);
        gB1[t] = pack_bf16(Gp[i2], Gp[i3]);
        gbv[t] = GB[n];
    }
    const float ab = ABv[0], bb = BBv[0];
    const f4* AWp = reinterpret_cast<const f4*>(AW);
    const f4* BWp = reinterpret_cast<const f4*>(BW);

    auto load_feats = [&](int nidx, unsigned grpL) -> Feats {
        Feats F;
        const unsigned row = grpL * 16u + (unsigned)m;
        const f4* Wp  = reinterpret_cast<const f4*>(W + (unsigned)nidx * 64u);
        const f4* L1p = reinterpret_cast<const f4*>(L1 + (size_t)row * 64u);
        const f4* L2p = reinterpret_cast<const f4*>(L2 + (size_t)row * 64u);
        F.w[0] = Wp[i0]; F.w[1] = Wp[i1]; F.w[2] = Wp[i2]; F.w[3] = Wp[i3];
        F.x[0] = __builtin_nontemporal_load(L1p + i0);
        F.x[1] = __builtin_nontemporal_load(L1p + i1);
        F.x[2] = __builtin_nontemporal_load(L1p + i2);
        F.x[3] = __builtin_nontemporal_load(L1p + i3);
        F.y[0] = __builtin_nontemporal_load(L2p + i0);
        F.y[1] = __builtin_nontemporal_load(L2p + i1);
        F.y[2] = __builtin_nontemporal_load(L2p + i2);
        F.y[3] = __builtin_nontemporal_load(L2p + i3);
        return F;
    };

    auto compute_store = [&](const Feats& F, unsigned grpC) {
        const unsigned row0 = grpC * 16u;
        // gates in f32
        float pa = dot4(F.w[0], AWp[i0]) + dot4(F.w[1], AWp[i1])
                 + dot4(F.w[2], AWp[i2]) + dot4(F.w[3], AWp[i3])
                 + dot4(F.x[0], AWp[16 + i0]) + dot4(F.x[1], AWp[16 + i1])
                 + dot4(F.x[2], AWp[16 + i2]) + dot4(F.x[3], AWp[16 + i3]);
        float pb = dot4(F.w[0], BWp[i0]) + dot4(F.w[1], BWp[i1])
                 + dot4(F.w[2], BWp[i2]) + dot4(F.w[3], BWp[i3])
                 + dot4(F.y[0], BWp[16 + i0]) + dot4(F.y[1], BWp[16 + i1])
                 + dot4(F.y[2], BWp[16 + i2]) + dot4(F.y[3], BWp[16 + i3]);
        // row m lives on lanes {m, m+16, m+32, m+48}
        pa += __shfl_xor(pa, 16); pa += __shfl_xor(pa, 32);
        pb += __shfl_xor(pb, 16); pb += __shfl_xor(pb, 32);
        const float alpha = pa + ab;
        const float beta  = pb + bb;

        const short8 a0 = pack_bf16(comb4(F.w[0], alpha, F.x[0], beta, F.y[0]),
                                    comb4(F.w[1], alpha, F.x[1], beta, F.y[1]));
        const short8 a1 = pack_bf16(comb4(F.w[2], alpha, F.x[2], beta, F.y[2]),
                                    comb4(F.w[3], alpha, F.x[3], beta, F.y[3]));

        f32x4 acc[4];
#pragma unroll
        for (int t = 0; t < 4; ++t) {
            acc[t][0] = gbv[t]; acc[t][1] = gbv[t]; acc[t][2] = gbv[t]; acc[t][3] = gbv[t];
            acc[t] = __builtin_amdgcn_mfma_f32_16x16x32_bf16(a0, gB0[t], acc[t], 0, 0, 0);
            acc[t] = __builtin_amdgcn_mfma_f32_16x16x32_bf16(a1, gB1[t], acc[t], 0, 0, 0);
        }
        // C layout col=lane&15, row=4g+reg (m89-verified); plain stores (WRITE=131 exact)
#pragma unroll
        for (int t = 0; t < 4; ++t) {
#pragma unroll
            for (int r = 0; r < 4; ++r) {
                out[(row0 + 4u * (unsigned)g + r) * 64u + (unsigned)(t * 16 + m)] = acc[t][r];
            }
        }
    };

    const unsigned grp0 = (unsigned)blockIdx.x * 4u + (unsigned)wid;

    if (grp0 + 3u * stride < nGroups && 4u * stride == nGroups) {
        // ---- fast path (bench shape): exactly 4 groups/wave, ONE basic block ----
        const unsigned g1 = grp0 + stride, g2 = g1 + stride, g3 = g2 + stride;
        // all node indices up front (independent, no chain in steady state)
        const int nv0 = nodes[grp0 * 16u + (unsigned)m];
        const int nv1 = nodes[g1   * 16u + (unsigned)m];
        const int nv2 = nodes[g2   * 16u + (unsigned)m];
        const int nv3 = nodes[g3   * 16u + (unsigned)m];

        Feats A = load_feats(nv0, grp0);     // 12 loads in flight
        Feats B = load_feats(nv1, g1);       // 24 in flight
        compute_store(A, grp0);              // waits only A's 12 (vmcnt(12))
        A = load_feats(nv2, g2);             // refill
        compute_store(B, g1);                // waits only B's 12
        B = load_feats(nv3, g3);             // refill
        compute_store(A, g2);
        compute_store(B, g3);
    } else {
        // ---- generic fallback (not taken in bench): simple serial loop ----
        for (unsigned grp = grp0; grp < nGroups; grp += stride) {
            const int nv = nodes[grp * 16u + (unsigned)m];
            Feats F = load_feats(nv, grp);
            compute_store(F, grp);
        }
    }
}

extern "C" void kernel_launch(void* const* d_in, const int* in_sizes, int n_in,
                              void* d_out, int out_size, void* d_ws, size_t ws_size,
                              hipStream_t stream) {
    const int*   nodes = (const int*)  d_in[0];
    const float* W     = (const float*)d_in[1];
    const float* L1    = (const float*)d_in[2];
    const float* L2    = (const float*)d_in[3];
    const float* AW    = (const float*)d_in[4];
    const float* AB    = (const float*)d_in[5];
    const float* BW    = (const float*)d_in[6];
    const float* BB    = (const float*)d_in[7];
    const float* GW    = (const float*)d_in[8];
    const float* GB    = (const float*)d_in[9];
    float* out = (float*)d_out;
    const int nrows = in_sizes[0];  // B = 524288

    // 2048 blocks x 4 waves = 8192 persistent waves, exactly 4 groups each
    hipLaunchKernelGGL(encoder_mfma, dim3(2048), dim3(256), 0, stream,
                       nodes, W, L1, L2, AW, AB, BW, BB, GW, GB, out, nrows);
}